// Round 15
// baseline (228.144 us; speedup 1.0000x reference)
//
#include <hip/hip_runtime.h>
#include <math.h>

#define EPS 0.3f

typedef __attribute__((ext_vector_type(8))) short bf16x8;
typedef __attribute__((ext_vector_type(4))) float f32x4;

__device__ __forceinline__ short f2bf(float f) {
    union { float f; unsigned u; } v; v.f = f;
    unsigned r = v.u + 0x7FFFu + ((v.u >> 16) & 1u);  // RNE
    return (short)(r >> 16);
}
__device__ __forceinline__ float bf2f(short s) {
    union { unsigned u; float f; } v;
    v.u = ((unsigned)(unsigned short)s) << 16;
    return v.f;
}
// pack two fp32 -> 2x bf16 in one int (low = first arg)
__device__ __forceinline__ int f2bf_pk(float lo, float hi) {
#if __has_builtin(__builtin_amdgcn_cvt_pk_bf16_f32)
    auto r = __builtin_amdgcn_cvt_pk_bf16_f32(lo, hi);
    int out; __builtin_memcpy(&out, &r, 4);
    return out;
#else
    return ((int)(unsigned short)f2bf(lo)) | (((int)(unsigned short)f2bf(hi)) << 16);
#endif
}
// tanh via HW exp: 1 - 2/(1+e^{2x}); saturates correctly, ~1e-6 rel err.
__device__ __forceinline__ float fast_tanh(float x) {
    return 1.0f - 2.0f / (1.0f + __expf(2.0f * x));
}

// ---- CSR build: two-level binned counting sort (bins = dst>>8) ----
// NOTE (R9): no cooperative fusion — grid.sync() ~40µs each at this size.
// NOTE (R15): N < 65536 and dst-local < 256, so edges pack to 4B (src|dstlo<<16)
// and the final CSR src array is ushort — halves all sort/index traffic.

// per-block LDS histogram of dst>>8 -> hist2d[bid][tid] (plain store, no init).
// Blocks 0..63 additionally convert w (64*256 fp32->bf16), 1 elem/thread.
__global__ __launch_bounds__(256) void coarse_hist(const int* __restrict__ dst,
                                                   int* __restrict__ hist2d, int E,
                                                   const float* __restrict__ w,
                                                   short* __restrict__ wb) {
    if (blockIdx.x < 64) {
        int i = blockIdx.x * 256 + threadIdx.x;
        wb[i] = f2bf(w[i]);
    }
    __shared__ int lh[256];
    lh[threadIdx.x] = 0;
    __syncthreads();
    for (int i = blockIdx.x * 256 + threadIdx.x; i < E; i += gridDim.x * 256)
        atomicAdd(&lh[dst[i] >> 8], 1);
    __syncthreads();
    hist2d[blockIdx.x * 256 + threadIdx.x] = lh[threadIdx.x];
}

// single block: sum hist2d columns (unroll-8 for MLP), exclusive scan; rs[N]=E
__global__ void coarse_scan(const int* __restrict__ hist2d, int* __restrict__ cbase,
                            int* __restrict__ ccur, int* __restrict__ rs,
                            int NBIN, int N, int E) {
    __shared__ int tmp[256];
    int tid = threadIdx.x;
    int v = 0;
    #pragma unroll 8
    for (int b = 0; b < 256; ++b) v += hist2d[b * 256 + tid];
    if (tid >= NBIN) v = 0;
    tmp[tid] = v;
    __syncthreads();
    #pragma unroll
    for (int off = 1; off < 256; off <<= 1) {
        int o = (tid >= off) ? tmp[tid - off] : 0;
        __syncthreads();
        tmp[tid] += o;
        __syncthreads();
    }
    if (tid < NBIN) { cbase[tid] = tmp[tid] - v; ccur[tid] = tmp[tid] - v; }
    if (tid == NBIN - 1) cbase[NBIN] = tmp[tid];
    if (tid == 0) rs[N] = E;
}

// partition edges into coarse-bin-grouped order; 4B packed entries
__global__ __launch_bounds__(256) void partition(const int* __restrict__ src,
                                                 const int* __restrict__ dst,
                                                 int* __restrict__ ccur,
                                                 unsigned* __restrict__ part, int E) {
    __shared__ int lh[256];
    __shared__ int lbase[256];
    int tid = threadIdx.x;
    int chunk = (E + gridDim.x - 1) / gridDim.x;
    int s0 = blockIdx.x * chunk;
    int s1 = min(s0 + chunk, E);
    lh[tid] = 0;
    __syncthreads();
    for (int i = s0 + tid; i < s1; i += 256) atomicAdd(&lh[dst[i] >> 8], 1);
    __syncthreads();
    int c = lh[tid];
    lbase[tid] = c ? atomicAdd(&ccur[tid], c) : 0;
    __syncthreads();
    lh[tid] = 0;                       // reuse as local cursor
    __syncthreads();
    for (int i = s0 + tid; i < s1; i += 256) {
        int t = dst[i];
        int b = t >> 8;
        int r = atomicAdd(&lh[b], 1);
        part[lbase[b] + r] = (unsigned)src[i] | ((unsigned)(t & 255) << 16);
    }
}

// one block per coarse bin: per-node LDS count + scan -> rs, d, CSR esrc (u16)
__global__ __launch_bounds__(256) void bin_csr(const unsigned* __restrict__ part,
                                               const int* __restrict__ cbase,
                                               int* __restrict__ rs, float* __restrict__ d,
                                               unsigned short* __restrict__ esrc, int N) {
    __shared__ int lcnt[256], s[256], lcur[256];
    int tid = threadIdx.x;
    int t0 = blockIdx.x << 8;
    int e0 = cbase[blockIdx.x], e1 = cbase[blockIdx.x + 1];
    lcnt[tid] = 0;
    __syncthreads();
    for (int i = e0 + tid; i < e1; i += 256) atomicAdd(&lcnt[(part[i] >> 16) & 255], 1);
    __syncthreads();
    int v = lcnt[tid];
    s[tid] = v;
    __syncthreads();
    #pragma unroll
    for (int off = 1; off < 256; off <<= 1) {
        int o = (tid >= off) ? s[tid - off] : 0;
        __syncthreads();
        s[tid] += o;
        __syncthreads();
    }
    int excl = s[tid] - v;
    int node = t0 + tid;
    if (node < N) {
        rs[node] = e0 + excl;
        d[node] = rsqrtf(fmaxf((float)v, 1.0f));
    }
    lcur[tid] = e0 + excl;
    __syncthreads();
    for (int i = e0 + tid; i < e1; i += 256) {
        unsigned e = part[i];
        int slot = atomicAdd(&lcur[(e >> 16) & 255], 1);
        esrc[slot] = (unsigned short)(e & 0xFFFFu);
    }
}

// x0 = relu(h @ w^T + b) in bf16; fused layer-0 gate dots (ga0, bd0=(gb0,d)).
// MFMA 16x16x32 bf16. A: [m=lane&15][k=quad*8+j]; D: col=lane&15, row=quad*4+reg.
#define LROW 264   // LDS row stride in shorts (256 + 8 pad): 528 B
__global__ __launch_bounds__(256) void t1_mfma(
    const float* __restrict__ h, const short* __restrict__ wb,
    const float* __restrict__ t1b, const float* __restrict__ gw,
    const float* __restrict__ dco, short* __restrict__ XAh,
    float* __restrict__ ga, float2* __restrict__ bd, int N)
{
    __shared__ short lh[4][16 * LROW];
    int wave = threadIdx.x >> 6;
    int lane = threadIdx.x & 63;
    int l15 = lane & 15, quad = lane >> 4;
    int M0 = (blockIdx.x * 4 + wave) * 16;
    if (M0 >= N) return;
    int rlim = N - M0;                         // rows valid in this tile (<=16)

    short* myl = lh[wave];
    const float* hb = h + (size_t)M0 * 256;
    #pragma unroll
    for (int r = 0; r < 16; ++r) {
        if (r < rlim) {
            float4 v = *(const float4*)&hb[(size_t)r * 256 + lane * 4];
            int2 sv; sv.x = f2bf_pk(v.x, v.y); sv.y = f2bf_pk(v.z, v.w);
            *(int2*)&myl[r * LROW + lane * 4] = sv;
        }
    }

    f32x4 acc[4];
    #pragma unroll
    for (int nt = 0; nt < 4; ++nt) acc[nt] = (f32x4){0.f, 0.f, 0.f, 0.f};

    const short* wq = wb + quad * 8;
    #pragma unroll
    for (int kc = 0; kc < 256; kc += 32) {
        bf16x8 af = *(const bf16x8*)&myl[l15 * LROW + kc + quad * 8];
        #pragma unroll
        for (int nt = 0; nt < 4; ++nt) {
            bf16x8 bf = *(const bf16x8*)(wq + (size_t)(nt * 16 + l15) * 256 + kc);
            acc[nt] = __builtin_amdgcn_mfma_f32_16x16x32_bf16(af, bf, acc[nt], 0, 0, 0);
        }
    }

    float pa[4] = {0.f, 0.f, 0.f, 0.f};
    float pb[4] = {0.f, 0.f, 0.f, 0.f};
    #pragma unroll
    for (int nt = 0; nt < 4; ++nt) {
        int n = nt * 16 + l15;
        float bias = t1b[n];
        float gd = gw[n], gs = gw[64 + n];
        #pragma unroll
        for (int r = 0; r < 4; ++r) {
            int row = quad * 4 + r;
            if (row < rlim) {
                float x = fmaxf(acc[nt][r] + bias, 0.f);
                XAh[(size_t)(M0 + row) * 64 + n] = f2bf(x);
                pa[r] += x * gd;
                pb[r] += x * gs;
            }
        }
    }
    #pragma unroll
    for (int off = 1; off < 16; off <<= 1) {
        #pragma unroll
        for (int r = 0; r < 4; ++r) {
            pa[r] += __shfl_xor(pa[r], off, 64);
            pb[r] += __shfl_xor(pb[r], off, 64);
        }
    }
    if (l15 == 0) {
        #pragma unroll
        for (int r = 0; r < 4; ++r) {
            int row = quad * 4 + r;
            if (row < rlim) {
                ga[M0 + row] = pa[r];
                float2 v; v.x = pb[r]; v.y = dco[M0 + row];
                bd[M0 + row] = v;
            }
        }
    }
}

// Gather core (8x8 layout + uniform edge-index preload).
// R13 post-mortem: __shfl under group-divergent exec reads 0 from inactive
// source lanes -> ALL bpermutes are hoisted to a fully-active preamble; the
// unrolled edge loop contains only loads/VALU under per-group guards.
// After the xor-reduce every lane holds the full row (features (lane&7)*8+k).
__device__ __forceinline__ void gather_core(
    const int* __restrict__ rs, const unsigned short* __restrict__ esrc,
    const float* __restrict__ a, const float2* __restrict__ bd,
    const short* __restrict__ xch, const short* __restrict__ rawh,
    float gbias, int t, int lane, float acc[8], float& dt_out)
{
    int g = lane >> 3;        // edge group 0..7
    int l = lane & 7;         // feature octet
    int beg = rs[t], end = rs[t + 1];
    int deg = end - beg;
    float atg = a[t] + gbias;
    float dt = bd[t].y;
    dt_out = dt;

    // one coalesced 2B/lane load covers up to 64 edges (Poisson lambda=16)
    int ev = (lane < deg) ? (int)esrc[beg + lane] : 0;
    // distribute: group g's k-th edge src = lane g+8k — all lanes active here
    int sarr[8];
    #pragma unroll
    for (int k = 0; k < 8; ++k) sarr[k] = __shfl(ev, g + 8 * k, 64);

    #pragma unroll
    for (int k = 0; k < 8; ++k) acc[k] = 0.f;
    if (g == 0) {
        bf16x8 rv = *(const bf16x8*)&rawh[(size_t)t * 64 + l * 8];
        #pragma unroll
        for (int k = 0; k < 8; ++k) acc[k] = EPS * bf2f(rv[k]);
    }

    int lim = min(deg, 64);
    #pragma unroll
    for (int k = 0; k < 8; ++k) {
        if (g + 8 * k < lim) {
            int s0 = sarr[k];
            float2 bd0 = bd[s0];
            bf16x8 x0 = *(const bf16x8*)&xch[(size_t)s0 * 64 + l * 8];
            float c0 = fast_tanh(atg + bd0.x) * dt * bd0.y;
            #pragma unroll
            for (int kk = 0; kk < 8; ++kk) acc[kk] += c0 * bf2f(x0[kk]);
        }
    }
    // rare tail: deg > 64 (Poisson(16) makes this ~never; kept for correctness)
    for (int i = beg + 64 + g; i < end; i += 8) {
        int s0 = (int)esrc[i];
        float2 bd0 = bd[s0];
        bf16x8 x0 = *(const bf16x8*)&xch[(size_t)s0 * 64 + l * 8];
        float c0 = fast_tanh(atg + bd0.x) * dt * bd0.y;
        #pragma unroll
        for (int k = 0; k < 8; ++k) acc[k] += c0 * bf2f(x0[k]);
    }

    // reduce across the 8 edge groups (lanes differing in bits 3,4,5)
    #pragma unroll
    for (int off = 8; off < 64; off <<= 1) {
        #pragma unroll
        for (int k = 0; k < 8; ++k) acc[k] += __shfl_xor(acc[k], off, 64);
    }
}

// layer 0: x1(bf16) = EPS*x0 + gather(x0); next-layer gate dots (ga1, bd1)
__global__ __launch_bounds__(256) void gather_mid(
    const int* __restrict__ rs, const unsigned short* __restrict__ esrc,
    const float* __restrict__ a, const float2* __restrict__ bd,
    const short* __restrict__ xch, const float* __restrict__ gbp,
    short* __restrict__ xnh, const float* __restrict__ gw_next,
    float* __restrict__ ga_next, float2* __restrict__ bd_next, int N)
{
    int tid = threadIdx.x;
    int t = blockIdx.x * 4 + (tid >> 6);
    if (t >= N) return;
    int lane = tid & 63;
    int g = lane >> 3, l = lane & 7;
    float acc[8], dt;
    gather_core(rs, esrc, a, bd, xch, xch, gbp[0], t, lane, acc, dt);

    if (g == 0) {
        int4 o;
        o.x = f2bf_pk(acc[0], acc[1]); o.y = f2bf_pk(acc[2], acc[3]);
        o.z = f2bf_pk(acc[4], acc[5]); o.w = f2bf_pk(acc[6], acc[7]);
        *(int4*)&xnh[(size_t)t * 64 + l * 8] = o;
    }
    float av = 0.f, bv = 0.f;
    #pragma unroll
    for (int k = 0; k < 8; ++k) {
        av += acc[k] * gw_next[l * 8 + k];
        bv += acc[k] * gw_next[64 + l * 8 + k];
    }
    #pragma unroll
    for (int off = 1; off < 8; off <<= 1) {
        av += __shfl_xor(av, off, 64);
        bv += __shfl_xor(bv, off, 64);
    }
    if (lane == 0) {
        ga_next[t] = av;
        float2 v; v.x = bv; v.y = dt;
        bd_next[t] = v;
    }
}

// layer 1: fused gather + t2 matmul + log_softmax; x2 never materialized.
__global__ __launch_bounds__(256) void gather_out(
    const int* __restrict__ rs, const unsigned short* __restrict__ esrc,
    const float* __restrict__ a, const float2* __restrict__ bd,
    const short* __restrict__ xch, const short* __restrict__ rawh,
    const float* __restrict__ gbp, const float* __restrict__ t2w,
    const float* __restrict__ t2b, float* __restrict__ out, int N)
{
    int tid = threadIdx.x;
    int t = blockIdx.x * 4 + (tid >> 6);
    if (t >= N) return;
    int lane = tid & 63;
    int g = lane >> 3, l = lane & 7;
    float acc[8], dt;
    gather_core(rs, esrc, a, bd, xch, rawh, gbp[1], t, lane, acc, dt);

    int j0 = 2 * g;
    const float* w0 = &t2w[(size_t)j0 * 64 + l * 8];
    const float* w1 = w0 + 64;
    float p0 = 0.f, p1 = 0.f;
    #pragma unroll
    for (int k = 0; k < 8; ++k) { p0 += acc[k] * w0[k]; p1 += acc[k] * w1[k]; }
    #pragma unroll
    for (int off = 1; off < 8; off <<= 1) {
        p0 += __shfl_xor(p0, off, 64);
        p1 += __shfl_xor(p1, off, 64);
    }
    float l0 = p0 + t2b[j0];
    float l1 = p1 + t2b[j0 + 1];
    float m = fmaxf(l0, l1);
    #pragma unroll
    for (int off = 8; off < 64; off <<= 1) m = fmaxf(m, __shfl_xor(m, off, 64));
    float s = __expf(l0 - m) + __expf(l1 - m);
    #pragma unroll
    for (int off = 8; off < 64; off <<= 1) s += __shfl_xor(s, off, 64);
    float lse = m + __logf(s);
    if (l == 0) {
        float2 o; o.x = l0 - lse; o.y = l1 - lse;
        *(float2*)&out[(size_t)t * 16 + j0] = o;
    }
}

extern "C" void kernel_launch(void* const* d_in, const int* in_sizes, int n_in,
                              void* d_out, int out_size, void* d_ws, size_t ws_size,
                              hipStream_t stream) {
    const float* h    = (const float*)d_in[0];
    const int*   src  = (const int*)d_in[1];
    const int*   dst  = (const int*)d_in[2];
    const float* t1w  = (const float*)d_in[3];
    const float* t1b  = (const float*)d_in[4];
    const float* gw   = (const float*)d_in[5];   // [2, 128]
    const float* gbia = (const float*)d_in[6];   // [2]
    const float* t2w  = (const float*)d_in[7];   // [16, 64]
    const float* t2b  = (const float*)d_in[8];   // [16]
    float* out = (float*)d_out;

    int N = in_sizes[0] / 256;                   // 50000 < 65536 (u16 packing)
    int E = in_sizes[1];
    int NBIN = (N + 255) / 256;                  // coarse bins (<=256)

    char* p = (char*)d_ws;
    short*    XAh    = (short*)p;       p += (size_t)N * 64 * 2;   // x0 bf16
    short*    XBh    = (short*)p;       p += (size_t)N * 64 * 2;   // x1 bf16
    float*    dco    = (float*)p;       p += (size_t)N * 4;
    float*    ga0    = (float*)p;       p += (size_t)N * 4;
    float*    ga1    = (float*)p;       p += (size_t)N * 4;
    float2*   bd0    = (float2*)p;      p += (size_t)N * 8;        // (gb0, d)
    float2*   bd1    = (float2*)p;      p += (size_t)N * 8;        // (gb1, d)
    int*      rs     = (int*)p;         p += (size_t)(N + 1) * 4;
    int*      hist2d = (int*)p;         p += 256 * 256 * 4;
    int*      cbase  = (int*)p;         p += 257 * 4;
    int*      ccur   = (int*)p;         p += 256 * 4;
    p = (char*)(((size_t)p + 15) & ~(size_t)15);
    unsigned* part   = (unsigned*)p;    p += (size_t)E * 4;        // src|dstlo<<16
    unsigned short* esrc = (unsigned short*)p; p += (size_t)E * 2; // CSR src u16
    p = (char*)(((size_t)p + 15) & ~(size_t)15);
    short*    wbf    = (short*)p;

    // ---- CSR build: binned counting sort; also emits rs[] and d[] ----
    coarse_hist<<<256, 256, 0, stream>>>(dst, hist2d, E, t1w, wbf);
    coarse_scan<<<1, 256, 0, stream>>>(hist2d, cbase, ccur, rs, NBIN, N, E);
    partition<<<256, 256, 0, stream>>>(src, dst, ccur, part, E);
    bin_csr<<<NBIN, 256, 0, stream>>>(part, cbase, rs, dco, esrc, N);

    // ---- t1 + relu (MFMA) with fused layer-0 gate dots ----
    t1_mfma<<<(N + 63) / 64, 256, 0, stream>>>(h, wbf, t1b, gw, dco, XAh, ga0, bd0, N);

    // ---- layer 0: x1(bf16) = EPS*x0 + gather(x0); fused layer-1 gate dots ----
    gather_mid<<<(N + 3) / 4, 256, 0, stream>>>(rs, esrc, ga0, bd0, XAh, gbia,
                                                XBh, gw + 128, ga1, bd1, N);

    // ---- layer 1: fused gather + t2 + log_softmax ----
    gather_out<<<(N + 3) / 4, 256, 0, stream>>>(rs, esrc, ga1, bd1, XBh, XAh, gbia,
                                                t2w, t2b, out, N);
}

// Round 16
// 216.634 us; speedup vs baseline: 1.0531x; 1.0531x over previous
//
#include <hip/hip_runtime.h>
#include <math.h>

#define EPS 0.3f

typedef __attribute__((ext_vector_type(8))) short bf16x8;
typedef __attribute__((ext_vector_type(4))) float f32x4;

__device__ __forceinline__ short f2bf(float f) {
    union { float f; unsigned u; } v; v.f = f;
    unsigned r = v.u + 0x7FFFu + ((v.u >> 16) & 1u);  // RNE
    return (short)(r >> 16);
}
__device__ __forceinline__ float bf2f(short s) {
    union { unsigned u; float f; } v;
    v.u = ((unsigned)(unsigned short)s) << 16;
    return v.f;
}
// pack two fp32 -> 2x bf16 in one int (low = first arg)
__device__ __forceinline__ int f2bf_pk(float lo, float hi) {
#if __has_builtin(__builtin_amdgcn_cvt_pk_bf16_f32)
    auto r = __builtin_amdgcn_cvt_pk_bf16_f32(lo, hi);
    int out; __builtin_memcpy(&out, &r, 4);
    return out;
#else
    return ((int)(unsigned short)f2bf(lo)) | (((int)(unsigned short)f2bf(hi)) << 16);
#endif
}
// tanh via HW exp: 1 - 2/(1+e^{2x}); saturates correctly, ~1e-6 rel err.
__device__ __forceinline__ float fast_tanh(float x) {
    return 1.0f - 2.0f / (1.0f + __expf(2.0f * x));
}

// ---- CSR build: two-level binned counting sort (bins = dst>>8) ----
// NOTE (R9): no cooperative fusion — grid.sync() ~40µs each at this size.
// NOTE (R15): N < 65536, dst-local < 256: edges pack to 4B, CSR src is u16.
// NOTE (R16): bin_csr is merged into the t1 launch (no data dependency once
// d is written straight into bd0/bd1.y by the bin_csr path).

// per-block LDS histogram of dst>>8 -> hist2d[bid][tid] (plain store, no init).
// Blocks 0..63 additionally convert w (64*256 fp32->bf16), 1 elem/thread.
__global__ __launch_bounds__(256) void coarse_hist(const int* __restrict__ dst,
                                                   int* __restrict__ hist2d, int E,
                                                   const float* __restrict__ w,
                                                   short* __restrict__ wb) {
    if (blockIdx.x < 64) {
        int i = blockIdx.x * 256 + threadIdx.x;
        wb[i] = f2bf(w[i]);
    }
    __shared__ int lh[256];
    lh[threadIdx.x] = 0;
    __syncthreads();
    for (int i = blockIdx.x * 256 + threadIdx.x; i < E; i += gridDim.x * 256)
        atomicAdd(&lh[dst[i] >> 8], 1);
    __syncthreads();
    hist2d[blockIdx.x * 256 + threadIdx.x] = lh[threadIdx.x];
}

// single block: sum hist2d columns (unroll-8 for MLP), exclusive scan; rs[N]=E
__global__ void coarse_scan(const int* __restrict__ hist2d, int* __restrict__ cbase,
                            int* __restrict__ ccur, int* __restrict__ rs,
                            int NBIN, int N, int E) {
    __shared__ int tmp[256];
    int tid = threadIdx.x;
    int v = 0;
    #pragma unroll 8
    for (int b = 0; b < 256; ++b) v += hist2d[b * 256 + tid];
    if (tid >= NBIN) v = 0;
    tmp[tid] = v;
    __syncthreads();
    #pragma unroll
    for (int off = 1; off < 256; off <<= 1) {
        int o = (tid >= off) ? tmp[tid - off] : 0;
        __syncthreads();
        tmp[tid] += o;
        __syncthreads();
    }
    if (tid < NBIN) { cbase[tid] = tmp[tid] - v; ccur[tid] = tmp[tid] - v; }
    if (tid == NBIN - 1) cbase[NBIN] = tmp[tid];
    if (tid == 0) rs[N] = E;
}

// partition edges into coarse-bin-grouped order; 4B packed entries
__global__ __launch_bounds__(256) void partition(const int* __restrict__ src,
                                                 const int* __restrict__ dst,
                                                 int* __restrict__ ccur,
                                                 unsigned* __restrict__ part, int E) {
    __shared__ int lh[256];
    __shared__ int lbase[256];
    int tid = threadIdx.x;
    int chunk = (E + gridDim.x - 1) / gridDim.x;
    int s0 = blockIdx.x * chunk;
    int s1 = min(s0 + chunk, E);
    lh[tid] = 0;
    __syncthreads();
    for (int i = s0 + tid; i < s1; i += 256) atomicAdd(&lh[dst[i] >> 8], 1);
    __syncthreads();
    int c = lh[tid];
    lbase[tid] = c ? atomicAdd(&ccur[tid], c) : 0;
    __syncthreads();
    lh[tid] = 0;                       // reuse as local cursor
    __syncthreads();
    for (int i = s0 + tid; i < s1; i += 256) {
        int t = dst[i];
        int b = t >> 8;
        int r = atomicAdd(&lh[b], 1);
        part[lbase[b] + r] = (unsigned)src[i] | ((unsigned)(t & 255) << 16);
    }
}

// x0 = relu(h @ w^T + b) in bf16; fused layer-0 gate dots.
// MFMA 16x16x32 bf16. A: [m=lane&15][k=quad*8+j]; D: col=lane&15, row=quad*4+reg.
#define LROW 264   // LDS row stride in shorts (256 + 8 pad): 528 B
// R16 merged kernel: blocks [0,NBIN) run the bin_csr path (rs, d->bd*.y, esrc);
// blocks [NBIN, NBIN+ceil(N/64)) run the t1 path (XAh, ga0, bd0.x).
// No dependency between paths: t1 writes bd0[n].x, bin_csr writes bd0[n].y /
// bd1[n].y — disjoint 4B fields. Block-uniform branch; LDS aliased.
__global__ __launch_bounds__(256) void csr_t1(
    const unsigned* __restrict__ part, const int* __restrict__ cbase,
    int* __restrict__ rs, unsigned short* __restrict__ esrc,
    const float* __restrict__ h, const short* __restrict__ wb,
    const float* __restrict__ t1b, const float* __restrict__ gw,
    short* __restrict__ XAh, float* __restrict__ ga0,
    float* __restrict__ bd0f, float* __restrict__ bd1f, int N, int NBIN)
{
    __shared__ short lds[4][16 * LROW];
    int tid = threadIdx.x;

    if ((int)blockIdx.x < NBIN) {
        // ---- bin_csr path: per-node LDS count + scan -> rs, d, CSR esrc ----
        int* lcnt = (int*)&lds[0][0];
        int* s    = lcnt + 256;
        int* lcur = s + 256;
        int t0 = blockIdx.x << 8;
        int e0 = cbase[blockIdx.x], e1 = cbase[blockIdx.x + 1];
        lcnt[tid] = 0;
        __syncthreads();
        for (int i = e0 + tid; i < e1; i += 256) atomicAdd(&lcnt[(part[i] >> 16) & 255], 1);
        __syncthreads();
        int v = lcnt[tid];
        s[tid] = v;
        __syncthreads();
        #pragma unroll
        for (int off = 1; off < 256; off <<= 1) {
            int o = (tid >= off) ? s[tid - off] : 0;
            __syncthreads();
            s[tid] += o;
            __syncthreads();
        }
        int excl = s[tid] - v;
        int node = t0 + tid;
        if (node < N) {
            rs[node] = e0 + excl;
            float dval = rsqrtf(fmaxf((float)v, 1.0f));
            bd0f[2 * node + 1] = dval;
            bd1f[2 * node + 1] = dval;
        }
        lcur[tid] = e0 + excl;
        __syncthreads();
        for (int i = e0 + tid; i < e1; i += 256) {
            unsigned e = part[i];
            int slot = atomicAdd(&lcur[(e >> 16) & 255], 1);
            esrc[slot] = (unsigned short)(e & 0xFFFFu);
        }
        return;
    }

    // ---- t1 path ----
    int bid = blockIdx.x - NBIN;
    int wave = tid >> 6;
    int lane = tid & 63;
    int l15 = lane & 15, quad = lane >> 4;
    int M0 = (bid * 4 + wave) * 16;
    if (M0 >= N) return;
    int rlim = N - M0;                         // rows valid in this tile (<=16)

    short* myl = lds[wave];
    const float* hb = h + (size_t)M0 * 256;
    #pragma unroll
    for (int r = 0; r < 16; ++r) {
        if (r < rlim) {
            float4 v = *(const float4*)&hb[(size_t)r * 256 + lane * 4];
            int2 sv; sv.x = f2bf_pk(v.x, v.y); sv.y = f2bf_pk(v.z, v.w);
            *(int2*)&myl[r * LROW + lane * 4] = sv;
        }
    }

    f32x4 acc[4];
    #pragma unroll
    for (int nt = 0; nt < 4; ++nt) acc[nt] = (f32x4){0.f, 0.f, 0.f, 0.f};

    const short* wq = wb + quad * 8;
    #pragma unroll
    for (int kc = 0; kc < 256; kc += 32) {
        bf16x8 af = *(const bf16x8*)&myl[l15 * LROW + kc + quad * 8];
        #pragma unroll
        for (int nt = 0; nt < 4; ++nt) {
            bf16x8 bf = *(const bf16x8*)(wq + (size_t)(nt * 16 + l15) * 256 + kc);
            acc[nt] = __builtin_amdgcn_mfma_f32_16x16x32_bf16(af, bf, acc[nt], 0, 0, 0);
        }
    }

    float pa[4] = {0.f, 0.f, 0.f, 0.f};
    float pb[4] = {0.f, 0.f, 0.f, 0.f};
    #pragma unroll
    for (int nt = 0; nt < 4; ++nt) {
        int n = nt * 16 + l15;
        float bias = t1b[n];
        float gd = gw[n], gs = gw[64 + n];
        #pragma unroll
        for (int r = 0; r < 4; ++r) {
            int row = quad * 4 + r;
            if (row < rlim) {
                float x = fmaxf(acc[nt][r] + bias, 0.f);
                XAh[(size_t)(M0 + row) * 64 + n] = f2bf(x);
                pa[r] += x * gd;
                pb[r] += x * gs;
            }
        }
    }
    #pragma unroll
    for (int off = 1; off < 16; off <<= 1) {
        #pragma unroll
        for (int r = 0; r < 4; ++r) {
            pa[r] += __shfl_xor(pa[r], off, 64);
            pb[r] += __shfl_xor(pb[r], off, 64);
        }
    }
    if (l15 == 0) {
        #pragma unroll
        for (int r = 0; r < 4; ++r) {
            int row = quad * 4 + r;
            if (row < rlim) {
                ga0[M0 + row] = pa[r];
                bd0f[2 * (M0 + row)] = pb[r];    // .x only; .y by bin_csr path
            }
        }
    }
}

// Gather core (8x8 layout + uniform edge-index preload).
// R13 post-mortem: __shfl under group-divergent exec reads 0 from inactive
// source lanes -> ALL bpermutes are hoisted to a fully-active preamble; the
// unrolled edge loop contains only loads/VALU under per-group guards.
// After the xor-reduce every lane holds the full row (features (lane&7)*8+k).
__device__ __forceinline__ void gather_core(
    const int* __restrict__ rs, const unsigned short* __restrict__ esrc,
    const float* __restrict__ a, const float2* __restrict__ bd,
    const short* __restrict__ xch, const short* __restrict__ rawh,
    float gbias, int t, int lane, float acc[8])
{
    int g = lane >> 3;        // edge group 0..7
    int l = lane & 7;         // feature octet
    int beg = rs[t], end = rs[t + 1];
    int deg = end - beg;
    float atg = a[t] + gbias;
    float dt = bd[t].y;

    // one coalesced 2B/lane load covers up to 64 edges (Poisson lambda=16)
    int ev = (lane < deg) ? (int)esrc[beg + lane] : 0;
    // distribute: group g's k-th edge src = lane g+8k — all lanes active here
    int sarr[8];
    #pragma unroll
    for (int k = 0; k < 8; ++k) sarr[k] = __shfl(ev, g + 8 * k, 64);

    #pragma unroll
    for (int k = 0; k < 8; ++k) acc[k] = 0.f;
    if (g == 0) {
        bf16x8 rv = *(const bf16x8*)&rawh[(size_t)t * 64 + l * 8];
        #pragma unroll
        for (int k = 0; k < 8; ++k) acc[k] = EPS * bf2f(rv[k]);
    }

    int lim = min(deg, 64);
    #pragma unroll
    for (int k = 0; k < 8; ++k) {
        if (g + 8 * k < lim) {
            int s0 = sarr[k];
            float2 bd0 = bd[s0];
            bf16x8 x0 = *(const bf16x8*)&xch[(size_t)s0 * 64 + l * 8];
            float c0 = fast_tanh(atg + bd0.x) * dt * bd0.y;
            #pragma unroll
            for (int kk = 0; kk < 8; ++kk) acc[kk] += c0 * bf2f(x0[kk]);
        }
    }
    // rare tail: deg > 64 (Poisson(16) makes this ~never; kept for correctness)
    for (int i = beg + 64 + g; i < end; i += 8) {
        int s0 = (int)esrc[i];
        float2 bd0 = bd[s0];
        bf16x8 x0 = *(const bf16x8*)&xch[(size_t)s0 * 64 + l * 8];
        float c0 = fast_tanh(atg + bd0.x) * dt * bd0.y;
        #pragma unroll
        for (int k = 0; k < 8; ++k) acc[k] += c0 * bf2f(x0[k]);
    }

    // reduce across the 8 edge groups (lanes differing in bits 3,4,5)
    #pragma unroll
    for (int off = 8; off < 64; off <<= 1) {
        #pragma unroll
        for (int k = 0; k < 8; ++k) acc[k] += __shfl_xor(acc[k], off, 64);
    }
}

// layer 0: x1(bf16) = EPS*x0 + gather(x0); next-layer gate dots (ga1, bd1.x)
__global__ __launch_bounds__(256) void gather_mid(
    const int* __restrict__ rs, const unsigned short* __restrict__ esrc,
    const float* __restrict__ a, const float2* __restrict__ bd,
    const short* __restrict__ xch, const float* __restrict__ gbp,
    short* __restrict__ xnh, const float* __restrict__ gw_next,
    float* __restrict__ ga_next, float* __restrict__ bd_next_f, int N)
{
    int tid = threadIdx.x;
    int t = blockIdx.x * 4 + (tid >> 6);
    if (t >= N) return;
    int lane = tid & 63;
    int g = lane >> 3, l = lane & 7;
    float acc[8];
    gather_core(rs, esrc, a, bd, xch, xch, gbp[0], t, lane, acc);

    if (g == 0) {
        int4 o;
        o.x = f2bf_pk(acc[0], acc[1]); o.y = f2bf_pk(acc[2], acc[3]);
        o.z = f2bf_pk(acc[4], acc[5]); o.w = f2bf_pk(acc[6], acc[7]);
        *(int4*)&xnh[(size_t)t * 64 + l * 8] = o;
    }
    float av = 0.f, bv = 0.f;
    #pragma unroll
    for (int k = 0; k < 8; ++k) {
        av += acc[k] * gw_next[l * 8 + k];
        bv += acc[k] * gw_next[64 + l * 8 + k];
    }
    #pragma unroll
    for (int off = 1; off < 8; off <<= 1) {
        av += __shfl_xor(av, off, 64);
        bv += __shfl_xor(bv, off, 64);
    }
    if (lane == 0) {
        ga_next[t] = av;
        bd_next_f[2 * t] = bv;       // .x only; .y (=d) prefilled by csr_t1
    }
}

// layer 1: fused gather + t2 matmul + log_softmax; x2 never materialized.
__global__ __launch_bounds__(256) void gather_out(
    const int* __restrict__ rs, const unsigned short* __restrict__ esrc,
    const float* __restrict__ a, const float2* __restrict__ bd,
    const short* __restrict__ xch, const short* __restrict__ rawh,
    const float* __restrict__ gbp, const float* __restrict__ t2w,
    const float* __restrict__ t2b, float* __restrict__ out, int N)
{
    int tid = threadIdx.x;
    int t = blockIdx.x * 4 + (tid >> 6);
    if (t >= N) return;
    int lane = tid & 63;
    int g = lane >> 3, l = lane & 7;
    float acc[8];
    gather_core(rs, esrc, a, bd, xch, rawh, gbp[1], t, lane, acc);

    int j0 = 2 * g;
    const float* w0 = &t2w[(size_t)j0 * 64 + l * 8];
    const float* w1 = w0 + 64;
    float p0 = 0.f, p1 = 0.f;
    #pragma unroll
    for (int k = 0; k < 8; ++k) { p0 += acc[k] * w0[k]; p1 += acc[k] * w1[k]; }
    #pragma unroll
    for (int off = 1; off < 8; off <<= 1) {
        p0 += __shfl_xor(p0, off, 64);
        p1 += __shfl_xor(p1, off, 64);
    }
    float l0 = p0 + t2b[j0];
    float l1 = p1 + t2b[j0 + 1];
    float m = fmaxf(l0, l1);
    #pragma unroll
    for (int off = 8; off < 64; off <<= 1) m = fmaxf(m, __shfl_xor(m, off, 64));
    float s = __expf(l0 - m) + __expf(l1 - m);
    #pragma unroll
    for (int off = 8; off < 64; off <<= 1) s += __shfl_xor(s, off, 64);
    float lse = m + __logf(s);
    if (l == 0) {
        float2 o; o.x = l0 - lse; o.y = l1 - lse;
        *(float2*)&out[(size_t)t * 16 + j0] = o;
    }
}

extern "C" void kernel_launch(void* const* d_in, const int* in_sizes, int n_in,
                              void* d_out, int out_size, void* d_ws, size_t ws_size,
                              hipStream_t stream) {
    const float* h    = (const float*)d_in[0];
    const int*   src  = (const int*)d_in[1];
    const int*   dst  = (const int*)d_in[2];
    const float* t1w  = (const float*)d_in[3];
    const float* t1b  = (const float*)d_in[4];
    const float* gw   = (const float*)d_in[5];   // [2, 128]
    const float* gbia = (const float*)d_in[6];   // [2]
    const float* t2w  = (const float*)d_in[7];   // [16, 64]
    const float* t2b  = (const float*)d_in[8];   // [16]
    float* out = (float*)d_out;

    int N = in_sizes[0] / 256;                   // 50000 < 65536 (u16 packing)
    int E = in_sizes[1];
    int NBIN = (N + 255) / 256;                  // coarse bins (<=256)

    char* p = (char*)d_ws;
    short*    XAh    = (short*)p;       p += (size_t)N * 64 * 2;   // x0 bf16
    short*    XBh    = (short*)p;       p += (size_t)N * 64 * 2;   // x1 bf16
    float*    ga0    = (float*)p;       p += (size_t)N * 4;
    float*    ga1    = (float*)p;       p += (size_t)N * 4;
    float2*   bd0    = (float2*)p;      p += (size_t)N * 8;        // (gb0, d)
    float2*   bd1    = (float2*)p;      p += (size_t)N * 8;        // (gb1, d)
    int*      rs     = (int*)p;         p += (size_t)(N + 1) * 4;
    int*      hist2d = (int*)p;         p += 256 * 256 * 4;
    int*      cbase  = (int*)p;         p += 257 * 4;
    int*      ccur   = (int*)p;         p += 256 * 4;
    p = (char*)(((size_t)p + 15) & ~(size_t)15);
    unsigned* part   = (unsigned*)p;    p += (size_t)E * 4;        // src|dstlo<<16
    unsigned short* esrc = (unsigned short*)p; p += (size_t)E * 2; // CSR src u16
    p = (char*)(((size_t)p + 15) & ~(size_t)15);
    short*    wbf    = (short*)p;

    // ---- CSR build front half ----
    coarse_hist<<<256, 256, 0, stream>>>(dst, hist2d, E, t1w, wbf);
    coarse_scan<<<1, 256, 0, stream>>>(hist2d, cbase, ccur, rs, NBIN, N, E);
    partition<<<256, 256, 0, stream>>>(src, dst, ccur, part, E);

    // ---- merged: bin_csr (blocks 0..NBIN-1) || t1+relu MFMA (rest) ----
    csr_t1<<<NBIN + (N + 63) / 64, 256, 0, stream>>>(
        part, cbase, rs, esrc, h, wbf, t1b, gw, XAh, ga0,
        (float*)bd0, (float*)bd1, N, NBIN);

    // ---- layer 0: x1(bf16) = EPS*x0 + gather(x0); fused layer-1 gate dots ----
    gather_mid<<<(N + 3) / 4, 256, 0, stream>>>(rs, esrc, ga0, bd0, XAh, gbia,
                                                XBh, gw + 128, ga1, (float*)bd1, N);

    // ---- layer 1: fused gather + t2 + log_softmax ----
    gather_out<<<(N + 3) / 4, 256, 0, stream>>>(rs, esrc, ga1, bd1, XBh, XAh, gbia,
                                                t2w, t2b, out, N);
}